// Round 5
// baseline (291.059 us; speedup 1.0000x reference)
//
#include <hip/hip_runtime.h>

#define N 16384
#define D 1024
#define EPSF 1e-8f
#define NSPLIT 4
#define CPS 4096 /* cols per split */
#define NCT 16   /* 256-wide col tiles per split */
#define QSCALE 448.0f

typedef __attribute__((ext_vector_type(4))) int i32x4;
typedef unsigned int u32;
typedef unsigned long long u64;

// LDS (bytes): A ring4 [0,64K) = 4 bufs x 16KB; B ring4 [64K,128K); mrg [128K,+4K)
#define LDS_Bb 65536
#define LDS_MRG 131072
#define LDS_TOT 135168

__device__ __forceinline__ void gload_lds16(const void* g, void* l) {
  __builtin_amdgcn_global_load_lds(
      (const __attribute__((address_space(1))) u32*)g,
      (__attribute__((address_space(3))) u32*)l, 16, 0, 0);
}

// ---------- kernel 1: row L2 norms + globally-scaled i8 matrix ----------

__global__ __launch_bounds__(256) void k_normalize(
    const float* __restrict__ x, signed char* __restrict__ xq,
    float* __restrict__ norms) {
  const int w = threadIdx.x >> 6, lane = threadIdx.x & 63;
  const int i = blockIdx.x * 4 + w;  // one wave per row
  const float4* xi = (const float4*)(x + (size_t)i * D);
  float4 v[4];
  float s = 0.f;
#pragma unroll
  for (int t = 0; t < 4; ++t) {
    v[t] = xi[lane + t * 64];
    s += v[t].x * v[t].x + v[t].y * v[t].y + v[t].z * v[t].z + v[t].w * v[t].w;
  }
#pragma unroll
  for (int sh = 32; sh; sh >>= 1) s += __shfl_xor(s, sh, 64);
  const float nrm = sqrtf(s);
  if (lane == 0) norms[i] = nrm;
  const float qs = QSCALE / fmaxf(nrm, EPSF);  // global scale: q = xn*QSCALE
  u32* xo = (u32*)(xq + (size_t)i * D);
#pragma unroll
  for (int t = 0; t < 4; ++t) {
    const int q0 = __float2int_rn(fminf(fmaxf(v[t].x * qs, -127.f), 127.f));
    const int q1 = __float2int_rn(fminf(fmaxf(v[t].y * qs, -127.f), 127.f));
    const int q2 = __float2int_rn(fminf(fmaxf(v[t].z * qs, -127.f), 127.f));
    const int q3 = __float2int_rn(fminf(fmaxf(v[t].w * qs, -127.f), 127.f));
    xo[lane + t * 64] = (u32)(q0 & 0xff) | ((u32)(q1 & 0xff) << 8) |
                        ((u32)(q2 & 0xff) << 16) | ((u32)(q3 & 0xff) << 24);
  }
}

// ---------- kernel 2: i8 MFMA streaming argmax, ring-4, 1 barrier/K-tile ----------
// 256 blocks (64 rowTiles x 4 splits), 512 thr = 8 waves (4M x 2N),
// per-wave C = 64x128. K-tile = 64 k. Ring-4 buffers, stage 3 tiles ahead,
// ONE barrier per K-tile (at top) + one counted vmcnt(4) (at end); no lgkm
// pins -- compiler emits counted lgkmcnt, waves drift within the iteration
// so ds_read bursts of late waves overlap MFMAs of early waves.

#define SG(gaddr, daddr) \
  gload_lds16(xqB + (gaddr) + srcLane, lds + (daddr) + w * 1024)

#define KT1(KT_)                                                               \
  {                                                                            \
    const int g = ct * 16 + (KT_);                                             \
    const int st = g + 3 > 255 ? 255 : g + 3; /* clamp: harmless re-stage */   \
    const int ktl = st & 15, cts = st >> 4;                                    \
    const size_t aG = (size_t)rowBase * 1024 + (size_t)(ktl * 64);             \
    const size_t bG = (size_t)(split * CPS + cts * 256) * 1024 +               \
                      (size_t)(ktl * 64);                                      \
    __builtin_amdgcn_s_barrier();                                              \
    asm volatile("" ::: "memory");                                             \
    SG(aG, (((KT_) + 3) & 3) * 16384);                                         \
    SG(aG + 131072, (((KT_) + 3) & 3) * 16384 + 8192);                         \
    SG(bG, LDS_Bb + (((KT_) + 3) & 3) * 16384);                                \
    SG(bG + 131072, LDS_Bb + (((KT_) + 3) & 3) * 16384 + 8192);                \
    i32x4 aa[4], bb[4];                                                        \
    _Pragma("unroll") for (int m = 0; m < 4; ++m) aa[m] =                      \
        *(const i32x4*)(lds + ((KT_)&3) * 16384 + aOff[m]);                    \
    _Pragma("unroll") for (int n = 0; n < 4; ++n) bb[n] =                      \
        *(const i32x4*)(lds + LDS_Bb + ((KT_)&3) * 16384 + bOff[n]);           \
    __builtin_amdgcn_s_setprio(1);                                             \
    _Pragma("unroll") for (int m = 0; m < 4; ++m)                              \
      _Pragma("unroll") for (int n = 0; n < 4; ++n)                            \
        acc[m][n] = __builtin_amdgcn_mfma_i32_16x16x64_i8(aa[m], bb[n],        \
                                                          acc[m][n], 0, 0, 0); \
    __builtin_amdgcn_s_setprio(0);                                             \
    _Pragma("unroll") for (int n = 0; n < 4; ++n) bb[n] =                      \
        *(const i32x4*)(lds + LDS_Bb + ((KT_)&3) * 16384 + bOff[4 + n]);       \
    __builtin_amdgcn_s_setprio(1);                                             \
    _Pragma("unroll") for (int m = 0; m < 4; ++m)                              \
      _Pragma("unroll") for (int n = 0; n < 4; ++n)                            \
        acc[m][4 + n] = __builtin_amdgcn_mfma_i32_16x16x64_i8(                 \
            aa[m], bb[n], acc[m][4 + n], 0, 0, 0);                             \
    __builtin_amdgcn_s_setprio(0);                                             \
    asm volatile("s_waitcnt vmcnt(4)" ::: "memory");                           \
  }

__global__ __launch_bounds__(512, 2) void k_argmax(
    const signed char* __restrict__ xq, u64* __restrict__ best_out) {
  extern __shared__ char lds[];
  const char* xqB = (const char*)xq;
  const int tid = (int)threadIdx.x, lane = tid & 63, w = tid >> 6;
  const int wr = w >> 1, wc = w & 1;
  const int rowTile = (int)blockIdx.x >> 2;
  const int split = (int)blockIdx.x & 3;
  const int rowBase = rowTile * 256;

  // LDS region: 256 rows x 64B K-tile window, 2 rows/128B line,
  // granule swizzle: inner = (((rr&1)<<6)|(q<<4)) ^ ((line&7)<<4)
  int aOff[4], bOff[8];
  const int q = lane >> 4, li = lane & 15;
#pragma unroll
  for (int m = 0; m < 4; ++m) {
    const int rr = wr * 64 + m * 16 + li;
    const int line = rr >> 1;
    aOff[m] = line * 128 + ((((rr & 1) << 6) | (q << 4)) ^ ((line & 7) << 4));
  }
#pragma unroll
  for (int nf = 0; nf < 8; ++nf) {
    const int rr = wc * 128 + nf * 16 + li;
    const int line = rr >> 1;
    bOff[nf] = line * 128 + ((((rr & 1) << 6) | (q << 4)) ^ ((line & 7) << 4));
  }
  // staging per-lane source offset (inverse swizzle; linear gload dest)
  const int posx = (lane & 7) ^ (lane >> 3);
  const int rrl = ((w * 8 + (lane >> 3)) << 1) | (posx >> 2);
  const int srcLane = rrl * 1024 + (posx & 3) * 16;

  int bestp[16];  // packed (dot<<3)|nf, int-ordered
  int bestc[16];
#pragma unroll
  for (int i = 0; i < 16; ++i) {
    bestp[i] = (int)0x80000000;
    bestc[i] = 0;
  }
  const int rB2 = wr * 64 + (q << 2);
  const int cB2 = wc * 128 + li;

  // prologue: stage tiles 0..2; vmcnt(4) -> tiles 0,1 retired (2 in flight
  // max is 8 loads = tiles t+2,t+3 in steady state)
  for (int p = 0; p < 3; ++p) {
    const size_t aG = (size_t)rowBase * 1024 + (size_t)(p * 64);
    const size_t bG = (size_t)(split * CPS) * 1024 + (size_t)(p * 64);
    SG(aG, p * 16384);
    SG(aG + 131072, p * 16384 + 8192);
    SG(bG, LDS_Bb + p * 16384);
    SG(bG + 131072, LDS_Bb + p * 16384 + 8192);
  }
  asm volatile("s_waitcnt vmcnt(4)" ::: "memory");

  i32x4 acc[4][8];
  for (int ct = 0; ct < NCT; ++ct) {
#pragma unroll
    for (int m = 0; m < 4; ++m)
#pragma unroll
      for (int n = 0; n < 8; ++n) acc[m][n] = (i32x4){0, 0, 0, 0};

    for (int kq = 0; kq < 4; ++kq) {
      KT1(kq * 4 + 0);
      KT1(kq * 4 + 1);
      KT1(kq * 4 + 2);
      KT1(kq * 4 + 3);
    }

    const int colBase = split * CPS + ct * 256;
    if (colBase == rowBase) {  // diagonal tile: mask self before max-fold
#pragma unroll
      for (int m = 0; m < 4; ++m)
#pragma unroll
        for (int r = 0; r < 4; ++r) {
          const int qs = m * 4 + r;
          const int grow = rB2 + m * 16 + r;
          int pm = bestp[qs];
#pragma unroll
          for (int nf = 0; nf < 8; ++nf) {
            int pv = (int)(((u32)acc[m][nf][r] << 3) | (u32)nf);
            if (grow == cB2 + nf * 16) pv = (int)0x80000000;
            pm = pm > pv ? pm : pv;
          }
          if (pm > bestp[qs]) {
            bestp[qs] = pm;
            bestc[qs] = colBase + cB2 + ((pm & 7) << 4);
          }
        }
    } else {
#pragma unroll
      for (int m = 0; m < 4; ++m)
#pragma unroll
        for (int r = 0; r < 4; ++r) {
          const int qs = m * 4 + r;
          int pm = (int)(((u32)acc[m][0][r] << 3));
#pragma unroll
          for (int nf = 1; nf < 8; ++nf) {
            const int pv = (int)(((u32)acc[m][nf][r] << 3) | (u32)nf);
            pm = pm > pv ? pm : pv;
          }
          if (pm > bestp[qs]) {
            bestp[qs] = pm;
            bestc[qs] = colBase + cB2 + ((pm & 7) << 4);
          }
        }
    }
  }

  // reduce across the 16 lanes sharing each row, then across wc via LDS
  u64* mrg = (u64*)(lds + LDS_MRG);
#pragma unroll
  for (int m = 0; m < 4; ++m)
#pragma unroll
    for (int r = 0; r < 4; ++r) {
      const int qs = m * 4 + r;
      const u32 mono = (u32)bestp[qs] ^ 0x80000000u;  // int -> ordered uint
      u64 p = ((u64)mono << 32) | (u32)bestc[qs];
#pragma unroll
      for (int sh = 1; sh < 16; sh <<= 1) {
        const u64 o = __shfl_xor(p, sh, 64);
        if (o > p) p = o;
      }
      if ((lane & 15) == 0) mrg[(rB2 + m * 16 + r) * 2 + wc] = p;
    }
  __syncthreads();
  if (tid < 256) {
    const u64 p0 = mrg[tid * 2], p1 = mrg[tid * 2 + 1];
    best_out[(size_t)(rowBase + tid) * NSPLIT + split] = p0 > p1 ? p0 : p1;
  }
}

// ---------- kernel 3: merge splits, exact fp32 distance + log ----------

__global__ __launch_bounds__(256) void k_dist(
    const float* __restrict__ x, const float* __restrict__ norms,
    const u64* __restrict__ best, float* __restrict__ logd) {
  const int w = threadIdx.x >> 6, lane = threadIdx.x & 63;
  const int i = blockIdx.x * 4 + w;
  u64 p = 0;
#pragma unroll
  for (int s = 0; s < NSPLIT; ++s) {
    const u64 qq = best[(size_t)i * NSPLIT + s];
    if (qq > p) p = qq;
  }
  const int j = (int)(p & 0xffffffffu);
  const float invi = 1.f / fmaxf(norms[i], EPSF);
  const float invj = 1.f / fmaxf(norms[j], EPSF);
  const float4* xi = (const float4*)(x + (size_t)i * D);
  const float4* xj = (const float4*)(x + (size_t)j * D);
  float s = 0.f;
#pragma unroll
  for (int t = 0; t < 4; ++t) {
    const float4 a = xi[lane + t * 64], b = xj[lane + t * 64];
    float d;
    d = a.x * invi - b.x * invj + EPSF; s += d * d;
    d = a.y * invi - b.y * invj + EPSF; s += d * d;
    d = a.z * invi - b.z * invj + EPSF; s += d * d;
    d = a.w * invi - b.w * invj + EPSF; s += d * d;
  }
#pragma unroll
  for (int sh = 32; sh; sh >>= 1) s += __shfl_xor(s, sh, 64);
  if (lane == 0) logd[i] = logf(sqrtf(s) + EPSF);
}

// ---------- kernel 4: deterministic fixed-order mean ----------

__global__ __launch_bounds__(256) void k_final(const float* __restrict__ logd,
                                               float* __restrict__ out) {
  __shared__ double red[256];
  double s = 0.0;
  for (int i = threadIdx.x; i < N; i += 256) s += (double)logd[i];
  red[threadIdx.x] = s;
  __syncthreads();
  for (int sh = 128; sh; sh >>= 1) {
    if ((int)threadIdx.x < sh) red[threadIdx.x] += red[threadIdx.x + sh];
    __syncthreads();
  }
  if (threadIdx.x == 0) out[0] = (float)(-red[0] / (double)N);
}

// ---------- launch ----------

extern "C" void kernel_launch(void* const* d_in, const int* in_sizes, int n_in,
                              void* d_out, int out_size, void* d_ws,
                              size_t ws_size, hipStream_t stream) {
  const float* x = (const float*)d_in[0];
  float* out = (float*)d_out;
  char* ws = (char*)d_ws;

  // ws: xq 16MB | norms 64KB | best 512KB | logd 64KB
  signed char* xq = (signed char*)ws;
  float* norms = (float*)(ws + 16777216);
  u64* best = (u64*)(ws + 16842752);
  float* logd = (float*)(ws + 17367040);

  k_normalize<<<N / 4, 256, 0, stream>>>(x, xq, norms);
  k_argmax<<<64 * NSPLIT, 512, LDS_TOT, stream>>>(xq, best);
  k_dist<<<N / 4, 256, 0, stream>>>(x, norms, best, logd);
  k_final<<<1, 256, 0, stream>>>(logd, out);
}

// Round 6
// 250.609 us; speedup vs baseline: 1.1614x; 1.1614x over previous
//
#include <hip/hip_runtime.h>
#include <math.h>

#define N 16384
#define D 1024
#define EPSF 1e-8f
#define QSCALE 448.0f
#define NSLOT 64 /* partial-best slots per row = tile count */

typedef __attribute__((ext_vector_type(4))) int i32x4;
typedef unsigned int u32;
typedef unsigned long long u64;

// LDS (bytes): A ring4 [0,64K); B ring4 [64K,128K); row mrg [128K,+4K);
// col mrg [132K,+8K)
#define LDS_Bb 65536
#define LDS_MRG 131072
#define LDS_CMRG 135168
#define LDS_TOT 143360

__device__ __forceinline__ void gload_lds16(const void* g, void* l) {
  __builtin_amdgcn_global_load_lds(
      (const __attribute__((address_space(1))) u32*)g,
      (__attribute__((address_space(3))) u32*)l, 16, 0, 0);
}

__device__ __forceinline__ u64 maxu64(u64 x, u64 y) { return x > y ? x : y; }

// ---------- kernel 1: row L2 norms + globally-scaled i8 matrix ----------

__global__ __launch_bounds__(256) void k_normalize(
    const float* __restrict__ x, signed char* __restrict__ xq,
    float* __restrict__ norms) {
  const int w = threadIdx.x >> 6, lane = threadIdx.x & 63;
  const int i = blockIdx.x * 4 + w;  // one wave per row
  const float4* xi = (const float4*)(x + (size_t)i * D);
  float4 v[4];
  float s = 0.f;
#pragma unroll
  for (int t = 0; t < 4; ++t) {
    v[t] = xi[lane + t * 64];
    s += v[t].x * v[t].x + v[t].y * v[t].y + v[t].z * v[t].z + v[t].w * v[t].w;
  }
#pragma unroll
  for (int sh = 32; sh; sh >>= 1) s += __shfl_xor(s, sh, 64);
  const float nrm = sqrtf(s);
  if (lane == 0) norms[i] = nrm;
  const float qs = QSCALE / fmaxf(nrm, EPSF);  // global scale: q = xn*QSCALE
  u32* xo = (u32*)(xq + (size_t)i * D);
#pragma unroll
  for (int t = 0; t < 4; ++t) {
    const int q0 = __float2int_rn(fminf(fmaxf(v[t].x * qs, -127.f), 127.f));
    const int q1 = __float2int_rn(fminf(fmaxf(v[t].y * qs, -127.f), 127.f));
    const int q2 = __float2int_rn(fminf(fmaxf(v[t].z * qs, -127.f), 127.f));
    const int q3 = __float2int_rn(fminf(fmaxf(v[t].w * qs, -127.f), 127.f));
    xo[lane + t * 64] = (u32)(q0 & 0xff) | ((u32)(q1 & 0xff) << 8) |
                        ((u32)(q2 & 0xff) << 16) | ((u32)(q3 & 0xff) << 24);
  }
}

// ---------- kernel 2: symmetric-triangle i8 MFMA argmax ----------
// 2080 blocks = upper-triangle tile pairs (a<=b) of 64 row-tiles (256 rows).
// 512 thr = 8 waves (4M x 2N); per-wave C = 64x128. 16 K-tiles of 64 k.
// Ring-4 LDS buffers, stage 3 ahead, 1 barrier + 1 counted vmcnt(8)/K-tile.
// Each block emits row-argmax partials (rows of a, slot b) AND col-argmax
// partials (rows of b, slot a) -- exact int symmetry S[i][j]==S[j][i].

#define SG(gaddr, daddr) \
  gload_lds16(xqB + (gaddr) + srcLane, lds + (daddr) + w * 1024)

#define KT1(KT_)                                                               \
  {                                                                            \
    const int g = (KT_);                                                       \
    const int st = g + 3 > 15 ? 15 : g + 3; /* clamp: dup-stage, harmless */   \
    const size_t aG = (size_t)aBase * 1024 + (size_t)(st * 64);                \
    const size_t bG = (size_t)bBase * 1024 + (size_t)(st * 64);                \
    __builtin_amdgcn_s_barrier();                                              \
    asm volatile("" ::: "memory");                                             \
    SG(aG, ((g + 3) & 3) * 16384);                                             \
    SG(aG + 131072, ((g + 3) & 3) * 16384 + 8192);                             \
    SG(bG, LDS_Bb + ((g + 3) & 3) * 16384);                                    \
    SG(bG + 131072, LDS_Bb + ((g + 3) & 3) * 16384 + 8192);                    \
    i32x4 aa[4], bb[4];                                                        \
    _Pragma("unroll") for (int m = 0; m < 4; ++m) aa[m] =                      \
        *(const i32x4*)(lds + ((g)&3) * 16384 + aOff[m]);                      \
    _Pragma("unroll") for (int n = 0; n < 4; ++n) bb[n] =                      \
        *(const i32x4*)(lds + LDS_Bb + ((g)&3) * 16384 + bOff[n]);             \
    __builtin_amdgcn_s_setprio(1);                                             \
    _Pragma("unroll") for (int m = 0; m < 4; ++m)                              \
      _Pragma("unroll") for (int n = 0; n < 4; ++n)                            \
        acc[m][n] = __builtin_amdgcn_mfma_i32_16x16x64_i8(aa[m], bb[n],        \
                                                          acc[m][n], 0, 0, 0); \
    __builtin_amdgcn_s_setprio(0);                                             \
    _Pragma("unroll") for (int n = 0; n < 4; ++n) bb[n] =                      \
        *(const i32x4*)(lds + LDS_Bb + ((g)&3) * 16384 + bOff[4 + n]);         \
    __builtin_amdgcn_s_setprio(1);                                             \
    _Pragma("unroll") for (int m = 0; m < 4; ++m)                              \
      _Pragma("unroll") for (int n = 0; n < 4; ++n)                            \
        acc[m][4 + n] = __builtin_amdgcn_mfma_i32_16x16x64_i8(                 \
            aa[m], bb[n], acc[m][4 + n], 0, 0, 0);                             \
    __builtin_amdgcn_s_setprio(0);                                             \
    asm volatile("s_waitcnt vmcnt(8)" ::: "memory");                           \
  }

__global__ __launch_bounds__(512, 2) void k_argmax(
    const signed char* __restrict__ xq, u64* __restrict__ best_out) {
  extern __shared__ char lds[];
  const char* xqB = (const char*)xq;
  const int tid = (int)threadIdx.x, lane = tid & 63, w = tid >> 6;
  const int wr = w >> 1, wc = w & 1;

  // decode upper-triangle pair (a <= b) from blockIdx
  const int t = (int)blockIdx.x;
  int a = (int)((129.0 - sqrt(129.0 * 129.0 - 8.0 * (double)t)) * 0.5);
  if (a < 0) a = 0;
  if (a > 63) a = 63;
  while (((a + 1) * 64 - ((a + 1) * a) / 2) <= t) ++a;
  while ((a * 64 - (a * (a - 1)) / 2) > t) --a;
  const int b = a + (t - (a * 64 - (a * (a - 1)) / 2));
  const int aBase = a * 256, bBase = b * 256;

  // LDS region: 256 rows x 64B K-tile window, 2 rows/128B line,
  // granule swizzle: inner = (((rr&1)<<6)|(q<<4)) ^ ((line&7)<<4)
  int aOff[4], bOff[8];
  const int q = lane >> 4, li = lane & 15;
#pragma unroll
  for (int m = 0; m < 4; ++m) {
    const int rr = wr * 64 + m * 16 + li;
    const int line = rr >> 1;
    aOff[m] = line * 128 + ((((rr & 1) << 6) | (q << 4)) ^ ((line & 7) << 4));
  }
#pragma unroll
  for (int nf = 0; nf < 8; ++nf) {
    const int rr = wc * 128 + nf * 16 + li;
    const int line = rr >> 1;
    bOff[nf] = line * 128 + ((((rr & 1) << 6) | (q << 4)) ^ ((line & 7) << 4));
  }
  // staging per-lane source offset (inverse swizzle; linear gload dest)
  const int posx = (lane & 7) ^ (lane >> 3);
  const int rrl = ((w * 8 + (lane >> 3)) << 1) | (posx >> 2);
  const int srcLane = rrl * 1024 + (posx & 3) * 16;

  const int rB2 = wr * 64 + (q << 2);
  const int cB2 = wc * 128 + li;

  // prologue: stage tiles 0..2; own-vmcnt(8) -> own tile-0 loads landed;
  // barrier at top of iter 0 publishes all waves' completions.
  for (int p = 0; p < 3; ++p) {
    const size_t aG = (size_t)aBase * 1024 + (size_t)(p * 64);
    const size_t bG = (size_t)bBase * 1024 + (size_t)(p * 64);
    SG(aG, p * 16384);
    SG(aG + 131072, p * 16384 + 8192);
    SG(bG, LDS_Bb + p * 16384);
    SG(bG + 131072, LDS_Bb + p * 16384 + 8192);
  }
  asm volatile("s_waitcnt vmcnt(8)" ::: "memory");

  i32x4 acc[4][8];
#pragma unroll
  for (int m = 0; m < 4; ++m)
#pragma unroll
    for (int n = 0; n < 8; ++n) acc[m][n] = (i32x4){0, 0, 0, 0};

  for (int kq = 0; kq < 4; ++kq) {
    KT1(kq * 4 + 0);
    KT1(kq * 4 + 1);
    KT1(kq * 4 + 2);
    KT1(kq * 4 + 3);
  }

  // ---- row-side fold: rows of panel a, cols of panel b ----
  int bestp[16], bestc[16];
#pragma unroll
  for (int m = 0; m < 4; ++m)
#pragma unroll
    for (int r = 0; r < 4; ++r) {
      const int qs = m * 4 + r;
      const int rl = rB2 + m * 16 + r;
      int pm = (int)0x80000000;
      if (a == b) {
#pragma unroll
        for (int nf = 0; nf < 8; ++nf) {
          int pv = (int)(((u32)acc[m][nf][r] << 3) | (u32)nf);
          if (rl == cB2 + nf * 16) pv = (int)0x80000000;
          pm = pm > pv ? pm : pv;
        }
      } else {
#pragma unroll
        for (int nf = 0; nf < 8; ++nf) {
          const int pv = (int)(((u32)acc[m][nf][r] << 3) | (u32)nf);
          pm = pm > pv ? pm : pv;
        }
      }
      bestp[qs] = pm;
      bestc[qs] = bBase + cB2 + ((pm & 7) << 4);
    }

  u64* mrg = (u64*)(lds + LDS_MRG);
#pragma unroll
  for (int m = 0; m < 4; ++m)
#pragma unroll
    for (int r = 0; r < 4; ++r) {
      const int qs = m * 4 + r;
      const u32 mono = (u32)bestp[qs] ^ 0x80000000u;
      u64 p = ((u64)mono << 32) | (u32)bestc[qs];
#pragma unroll
      for (int sh = 1; sh < 16; sh <<= 1) p = maxu64(p, __shfl_xor(p, sh, 64));
      if (li == 0) mrg[(rB2 + m * 16 + r) * 2 + wc] = p;
    }

  // ---- col-side fold: rows of panel b (candidates = rows of panel a) ----
  if (a != b) {
    u64* cmrg = (u64*)(lds + LDS_CMRG);
#pragma unroll
    for (int nf = 0; nf < 8; ++nf) {
      int pv = (int)0x80000000;
#pragma unroll
      for (int m = 0; m < 4; ++m)
#pragma unroll
        for (int r = 0; r < 4; ++r) {
          const int c = (int)(((u32)acc[m][nf][r] << 4) | (u32)(m * 4 + r));
          pv = pv > c ? pv : c;
        }
      const int mm = (pv >> 2) & 3, rr2 = pv & 3;
      const int growi = aBase + wr * 64 + mm * 16 + q * 4 + rr2;
      u64 p = ((u64)((u32)pv ^ 0x80000000u) << 32) | (u32)growi;
      p = maxu64(p, __shfl_xor(p, 16, 64));
      p = maxu64(p, __shfl_xor(p, 32, 64));
      if (q == 0) cmrg[(wc * 128 + nf * 16 + li) * 4 + wr] = p;
    }
  }
  __syncthreads();

  if (tid < 256) {
    // row-side: rows of a, slot b
    const u64 p0 = mrg[tid * 2], p1 = mrg[tid * 2 + 1];
    const u64 p = maxu64(p0, p1);
    const int pm = (int)((u32)(p >> 32) ^ 0x80000000u);
    const int dot = pm >> 3;  // arith shift recovers dot (floor)
    best_out[(size_t)(aBase + tid) * NSLOT + b] =
        ((u64)((u32)dot ^ 0x80000000u) << 32) | (p & 0xffffffffu);
    if (a != b) {
      u64* cmrg = (u64*)(lds + LDS_CMRG);
      u64 c = maxu64(maxu64(cmrg[tid * 4], cmrg[tid * 4 + 1]),
                     maxu64(cmrg[tid * 4 + 2], cmrg[tid * 4 + 3]));
      const int pv = (int)((u32)(c >> 32) ^ 0x80000000u);
      const int dotc = pv >> 4;
      best_out[(size_t)(bBase + tid) * NSLOT + a] =
          ((u64)((u32)dotc ^ 0x80000000u) << 32) | (c & 0xffffffffu);
    }
  }
}

// ---------- kernel 3: merge 64 slots, exact fp32 distance + log ----------

__global__ __launch_bounds__(256) void k_dist(
    const float* __restrict__ x, const float* __restrict__ norms,
    const u64* __restrict__ best, float* __restrict__ logd) {
  const int w = threadIdx.x >> 6, lane = threadIdx.x & 63;
  const int i = blockIdx.x * 4 + w;
  u64 p = best[(size_t)i * NSLOT + lane];
#pragma unroll
  for (int sh = 32; sh; sh >>= 1) {
    const u64 o = __shfl_xor(p, sh, 64);
    if (o > p) p = o;
  }
  const int j = (int)(p & 0xffffffffu);
  const float invi = 1.f / fmaxf(norms[i], EPSF);
  const float invj = 1.f / fmaxf(norms[j], EPSF);
  const float4* xi = (const float4*)(x + (size_t)i * D);
  const float4* xj = (const float4*)(x + (size_t)j * D);
  float s = 0.f;
#pragma unroll
  for (int t = 0; t < 4; ++t) {
    const float4 av = xi[lane + t * 64], bv = xj[lane + t * 64];
    float d;
    d = av.x * invi - bv.x * invj + EPSF; s += d * d;
    d = av.y * invi - bv.y * invj + EPSF; s += d * d;
    d = av.z * invi - bv.z * invj + EPSF; s += d * d;
    d = av.w * invi - bv.w * invj + EPSF; s += d * d;
  }
#pragma unroll
  for (int sh = 32; sh; sh >>= 1) s += __shfl_xor(s, sh, 64);
  if (lane == 0) logd[i] = logf(sqrtf(s) + EPSF);
}

// ---------- kernel 4: deterministic fixed-order mean ----------

__global__ __launch_bounds__(256) void k_final(const float* __restrict__ logd,
                                               float* __restrict__ out) {
  __shared__ double red[256];
  double s = 0.0;
  for (int i = threadIdx.x; i < N; i += 256) s += (double)logd[i];
  red[threadIdx.x] = s;
  __syncthreads();
  for (int sh = 128; sh; sh >>= 1) {
    if ((int)threadIdx.x < sh) red[threadIdx.x] += red[threadIdx.x + sh];
    __syncthreads();
  }
  if (threadIdx.x == 0) out[0] = (float)(-red[0] / (double)N);
}

// ---------- launch ----------

extern "C" void kernel_launch(void* const* d_in, const int* in_sizes, int n_in,
                              void* d_out, int out_size, void* d_ws,
                              size_t ws_size, hipStream_t stream) {
  const float* x = (const float*)d_in[0];
  float* out = (float*)d_out;
  char* ws = (char*)d_ws;

  // ws: xq 16MB | norms 64KB | best N*64*8 = 8MB | logd 64KB  (~24.3 MB)
  signed char* xq = (signed char*)ws;
  float* norms = (float*)(ws + 16777216);
  u64* best = (u64*)(ws + 16842752);
  float* logd = (float*)(ws + 16842752 + 8388608);

  k_normalize<<<N / 4, 256, 0, stream>>>(x, xq, norms);
  k_argmax<<<2080, 512, LDS_TOT, stream>>>(xq, best);
  k_dist<<<N / 4, 256, 0, stream>>>(x, norms, best, logd);
  k_final<<<1, 256, 0, stream>>>(logd, out);
}

// Round 7
// 244.582 us; speedup vs baseline: 1.1900x; 1.0246x over previous
//
#include <hip/hip_runtime.h>

#define N 16384
#define D 1024
#define EPSF 1e-8f
#define QSCALE 448.0f

typedef __attribute__((ext_vector_type(4))) int i32x4;
typedef unsigned int u32;
typedef unsigned long long u64;

// LDS (bytes): A ring4 [0,64K) = 4 bufs x 16KB; B ring4 [64K,128K)
#define LDS_Bb 65536
#define LDS_TOT 131072

__device__ __forceinline__ void gload_lds16(const void* g, void* l) {
  __builtin_amdgcn_global_load_lds(
      (const __attribute__((address_space(1))) u32*)g,
      (__attribute__((address_space(3))) u32*)l, 16, 0, 0);
}

__device__ __forceinline__ u64 maxu64(u64 x, u64 y) { return x > y ? x : y; }

// ---------- kernel 1: row L2 norms + globally-scaled i8 matrix + zero best ----------

__global__ __launch_bounds__(256) void k_normalize(
    const float* __restrict__ x, signed char* __restrict__ xq,
    float* __restrict__ norms, u64* __restrict__ best) {
  const int w = threadIdx.x >> 6, lane = threadIdx.x & 63;
  const int i = blockIdx.x * 4 + w;  // one wave per row
  if (threadIdx.x < 4) best[(size_t)blockIdx.x * 4 + threadIdx.x] = 0;
  const float4* xi = (const float4*)(x + (size_t)i * D);
  float4 v[4];
  float s = 0.f;
#pragma unroll
  for (int t = 0; t < 4; ++t) {
    v[t] = xi[lane + t * 64];
    s += v[t].x * v[t].x + v[t].y * v[t].y + v[t].z * v[t].z + v[t].w * v[t].w;
  }
#pragma unroll
  for (int sh = 32; sh; sh >>= 1) s += __shfl_xor(s, sh, 64);
  const float nrm = sqrtf(s);
  if (lane == 0) norms[i] = nrm;
  const float qs = QSCALE / fmaxf(nrm, EPSF);  // global scale: q = xn*QSCALE
  u32* xo = (u32*)(xq + (size_t)i * D);
#pragma unroll
  for (int t = 0; t < 4; ++t) {
    const int q0 = __float2int_rn(fminf(fmaxf(v[t].x * qs, -127.f), 127.f));
    const int q1 = __float2int_rn(fminf(fmaxf(v[t].y * qs, -127.f), 127.f));
    const int q2 = __float2int_rn(fminf(fmaxf(v[t].z * qs, -127.f), 127.f));
    const int q3 = __float2int_rn(fminf(fmaxf(v[t].w * qs, -127.f), 127.f));
    xo[lane + t * 64] = (u32)(q0 & 0xff) | ((u32)(q1 & 0xff) << 8) |
                        ((u32)(q2 & 0xff) << 16) | ((u32)(q3 & 0xff) << 24);
  }
}

// ---------- kernel 2: strip-mined symmetric-triangle i8 MFMA argmax ----------
// 544 blocks: row-panel a + strip of up to 4 b-tiles (b0-aligned, b>=a).
// 512 thr = 8 waves (4M x 2N); per-wave C = 64x128. Ring-4 K-tile pipeline
// runs across the whole strip (global K-tile counter), 1 barrier + counted
// vmcnt(8) per K-tile. Row-side argmax kept in registers across the strip;
// col-side folded per pair; both published via deterministic u64 atomicMax.

#define SG(gaddr, daddr) \
  gload_lds16(xqB + (gaddr) + srcLane, lds + (daddr) + w * 1024)

#define KT1(KT_)                                                               \
  {                                                                            \
    const int gs_ = pp * 16 + (KT_) + 3;                                       \
    const int gcl = gs_ > gmax ? gmax : gs_; /* clamp: dup-stage, unread */    \
    const int sk = gcl & 15;                                                   \
    const int sb = blo + (gcl >> 4);                                           \
    const size_t aG = aPan + (size_t)(sk * 64);                                \
    const size_t bG = (size_t)sb * 262144 + (size_t)(sk * 64);                 \
    __builtin_amdgcn_s_barrier();                                              \
    asm volatile("" ::: "memory");                                             \
    SG(aG, (((KT_) + 3) & 3) * 16384);                                         \
    SG(aG + 131072, (((KT_) + 3) & 3) * 16384 + 8192);                         \
    SG(bG, LDS_Bb + (((KT_) + 3) & 3) * 16384);                                \
    SG(bG + 131072, LDS_Bb + (((KT_) + 3) & 3) * 16384 + 8192);                \
    i32x4 aa[4], bb[4];                                                        \
    _Pragma("unroll") for (int m = 0; m < 4; ++m) aa[m] =                      \
        *(const i32x4*)(lds + ((KT_)&3) * 16384 + aOff[m]);                    \
    _Pragma("unroll") for (int n = 0; n < 4; ++n) bb[n] =                      \
        *(const i32x4*)(lds + LDS_Bb + ((KT_)&3) * 16384 + bOff[n]);           \
    __builtin_amdgcn_s_setprio(1);                                             \
    _Pragma("unroll") for (int m = 0; m < 4; ++m)                              \
      _Pragma("unroll") for (int n = 0; n < 4; ++n)                            \
        acc[m][n] = __builtin_amdgcn_mfma_i32_16x16x64_i8(aa[m], bb[n],        \
                                                          acc[m][n], 0, 0, 0); \
    __builtin_amdgcn_s_setprio(0);                                             \
    _Pragma("unroll") for (int n = 0; n < 4; ++n) bb[n] =                      \
        *(const i32x4*)(lds + LDS_Bb + ((KT_)&3) * 16384 + bOff[4 + n]);       \
    __builtin_amdgcn_s_setprio(1);                                             \
    _Pragma("unroll") for (int m = 0; m < 4; ++m)                              \
      _Pragma("unroll") for (int n = 0; n < 4; ++n)                            \
        acc[m][4 + n] = __builtin_amdgcn_mfma_i32_16x16x64_i8(                 \
            aa[m], bb[n], acc[m][4 + n], 0, 0, 0);                             \
    __builtin_amdgcn_s_setprio(0);                                             \
    asm volatile("s_waitcnt vmcnt(8)" ::: "memory");                           \
  }

__global__ __launch_bounds__(512, 2) void k_argmax(
    const signed char* __restrict__ xq, u64* __restrict__ best) {
  extern __shared__ char lds[];
  const char* xqB = (const char*)xq;
  const int tid = (int)threadIdx.x, lane = tid & 63, w = tid >> 6;
  const int wr = w >> 1, wc = w & 1;

  // decode strip: group g = a>>2 has 4 rows x (16-g) strips each
  int g = 0, cum = 0;
  {
    const int bid = (int)blockIdx.x;
    while (cum + 4 * (16 - g) <= bid) {
      cum += 4 * (16 - g);
      ++g;
    }
    cum = bid - cum;
  }
  const int a = g * 4 + cum / (16 - g);
  const int s = cum % (16 - g);
  const int b0 = 4 * (g + s);
  const int blo = a > b0 ? a : b0;
  const int np = b0 + 4 - blo;  // pairs in this strip (1..4)
  const int gmax = np * 16 - 1; // last global K-tile index
  const int aBase = a * 256;
  const size_t aPan = (size_t)a * 262144;

  // LDS region: 256 rows x 64B K-tile window, 2 rows/128B line,
  // granule swizzle: inner = (((rr&1)<<6)|(q<<4)) ^ ((line&7)<<4)
  int aOff[4], bOff[8];
  const int q = lane >> 4, li = lane & 15;
#pragma unroll
  for (int m = 0; m < 4; ++m) {
    const int rr = wr * 64 + m * 16 + li;
    const int line = rr >> 1;
    aOff[m] = line * 128 + ((((rr & 1) << 6) | (q << 4)) ^ ((line & 7) << 4));
  }
#pragma unroll
  for (int nf = 0; nf < 8; ++nf) {
    const int rr = wc * 128 + nf * 16 + li;
    const int line = rr >> 1;
    bOff[nf] = line * 128 + ((((rr & 1) << 6) | (q << 4)) ^ ((line & 7) << 4));
  }
  // staging per-lane source offset (inverse swizzle; linear gload dest)
  const int posx = (lane & 7) ^ (lane >> 3);
  const int rrl = ((w * 8 + (lane >> 3)) << 1) | (posx >> 2);
  const int srcLane = rrl * 1024 + (posx & 3) * 16;

  const int rB2 = wr * 64 + (q << 2);
  const int cB2 = wc * 128 + li;

  int bestp[16], bestc[16];  // row-side running best across the strip
#pragma unroll
  for (int i = 0; i < 16; ++i) {
    bestp[i] = (int)0x80000000;
    bestc[i] = 0;
  }

  // prologue: stage global K-tiles 0..2 into ring slots 0..2
  for (int p = 0; p < 3; ++p) {
    const size_t aG = aPan + (size_t)(p * 64);
    const size_t bG = (size_t)blo * 262144 + (size_t)(p * 64);
    SG(aG, p * 16384);
    SG(aG + 131072, p * 16384 + 8192);
    SG(bG, LDS_Bb + p * 16384);
    SG(bG + 131072, LDS_Bb + p * 16384 + 8192);
  }
  asm volatile("s_waitcnt vmcnt(8)" ::: "memory");

  i32x4 acc[4][8];
  for (int pp = 0; pp < np; ++pp) {
    const int bT = blo + pp;
    const int colBase = bT * 256;
#pragma unroll
    for (int m = 0; m < 4; ++m)
#pragma unroll
      for (int n = 0; n < 8; ++n) acc[m][n] = (i32x4){0, 0, 0, 0};

    for (int kq = 0; kq < 4; ++kq) {
      KT1(kq * 4 + 0);
      KT1(kq * 4 + 1);
      KT1(kq * 4 + 2);
      KT1(kq * 4 + 3);
    }

    // ---- row-side running update (rows of a over cols of bT) ----
    if (bT == a) {  // diagonal pair: mask self-similarity
#pragma unroll
      for (int m = 0; m < 4; ++m)
#pragma unroll
        for (int r = 0; r < 4; ++r) {
          const int qs = m * 4 + r;
          const int rl = rB2 + m * 16 + r;
          int pm = (int)0x80000000;
#pragma unroll
          for (int nf = 0; nf < 8; ++nf) {
            int pv = (int)(((u32)acc[m][nf][r] << 3) | (u32)nf);
            if (rl == cB2 + nf * 16) pv = (int)0x80000000;
            pm = pm > pv ? pm : pv;
          }
          if (pm > bestp[qs]) {
            bestp[qs] = pm;
            bestc[qs] = colBase + cB2 + ((pm & 7) << 4);
          }
        }
    } else {
#pragma unroll
      for (int m = 0; m < 4; ++m)
#pragma unroll
        for (int r = 0; r < 4; ++r) {
          const int qs = m * 4 + r;
          int pm = (int)0x80000000;
#pragma unroll
          for (int nf = 0; nf < 8; ++nf) {
            const int pv = (int)(((u32)acc[m][nf][r] << 3) | (u32)nf);
            pm = pm > pv ? pm : pv;
          }
          if (pm > bestp[qs]) {
            bestp[qs] = pm;
            bestc[qs] = colBase + cB2 + ((pm & 7) << 4);
          }
        }

      // ---- col-side fold (rows of bT; candidates = rows of a) ----
#pragma unroll
      for (int nf = 0; nf < 8; ++nf) {
        int pv = (int)0x80000000;
#pragma unroll
        for (int m = 0; m < 4; ++m)
#pragma unroll
          for (int r = 0; r < 4; ++r) {
            const int c =
                (int)(((u32)acc[m][nf][r] << 6) | (u32)(m * 16 + q * 4 + r));
            pv = pv > c ? pv : c;
          }
        {
          const int o1 = __shfl_xor(pv, 16, 64);
          pv = pv > o1 ? pv : o1;
          const int o2 = __shfl_xor(pv, 32, 64);
          pv = pv > o2 ? pv : o2;
        }
        if (q == 0) {
          const int dot = pv >> 6;  // exact (no overflow in <<6)
          const int grow = aBase + wr * 64 + (pv & 63);
          const u64 pk =
              ((u64)((u32)dot ^ 0x80000000u) << 32) | (u32)grow;
          atomicMax(best + (colBase + cB2 + nf * 16), pk);
        }
      }
    }
  }

  // ---- row-side final: fold 16 col-lanes, publish via atomicMax ----
#pragma unroll
  for (int m = 0; m < 4; ++m)
#pragma unroll
    for (int r = 0; r < 4; ++r) {
      const int qs = m * 4 + r;
      const u32 mono = (u32)(bestp[qs] >> 3) ^ 0x80000000u;
      u64 p = ((u64)mono << 32) | (u32)bestc[qs];
#pragma unroll
      for (int sh = 1; sh < 16; sh <<= 1) p = maxu64(p, __shfl_xor(p, sh, 64));
      if (li == 0) atomicMax(best + (aBase + rB2 + m * 16 + r), p);
    }
}

// ---------- kernel 3: exact fp32 distance + log ----------

__global__ __launch_bounds__(256) void k_dist(
    const float* __restrict__ x, const float* __restrict__ norms,
    const u64* __restrict__ best, float* __restrict__ logd) {
  const int w = threadIdx.x >> 6, lane = threadIdx.x & 63;
  const int i = blockIdx.x * 4 + w;
  const u64 p = best[i];
  const int j = (int)(p & 0xffffffffu);
  const float invi = 1.f / fmaxf(norms[i], EPSF);
  const float invj = 1.f / fmaxf(norms[j], EPSF);
  const float4* xi = (const float4*)(x + (size_t)i * D);
  const float4* xj = (const float4*)(x + (size_t)j * D);
  float s = 0.f;
#pragma unroll
  for (int t = 0; t < 4; ++t) {
    const float4 av = xi[lane + t * 64], bv = xj[lane + t * 64];
    float d;
    d = av.x * invi - bv.x * invj + EPSF; s += d * d;
    d = av.y * invi - bv.y * invj + EPSF; s += d * d;
    d = av.z * invi - bv.z * invj + EPSF; s += d * d;
    d = av.w * invi - bv.w * invj + EPSF; s += d * d;
  }
#pragma unroll
  for (int sh = 32; sh; sh >>= 1) s += __shfl_xor(s, sh, 64);
  if (lane == 0) logd[i] = logf(sqrtf(s) + EPSF);
}

// ---------- kernel 4: deterministic fixed-order mean ----------

__global__ __launch_bounds__(256) void k_final(const float* __restrict__ logd,
                                               float* __restrict__ out) {
  __shared__ double red[256];
  double s = 0.0;
  for (int i = threadIdx.x; i < N; i += 256) s += (double)logd[i];
  red[threadIdx.x] = s;
  __syncthreads();
  for (int sh = 128; sh; sh >>= 1) {
    if ((int)threadIdx.x < sh) red[threadIdx.x] += red[threadIdx.x + sh];
    __syncthreads();
  }
  if (threadIdx.x == 0) out[0] = (float)(-red[0] / (double)N);
}

// ---------- launch ----------

extern "C" void kernel_launch(void* const* d_in, const int* in_sizes, int n_in,
                              void* d_out, int out_size, void* d_ws,
                              size_t ws_size, hipStream_t stream) {
  const float* x = (const float*)d_in[0];
  float* out = (float*)d_out;
  char* ws = (char*)d_ws;

  // ws: xq 16MB | norms 64KB | best N*8 = 128KB | logd 64KB
  signed char* xq = (signed char*)ws;
  float* norms = (float*)(ws + 16777216);
  u64* best = (u64*)(ws + 16842752);
  float* logd = (float*)(ws + 16842752 + 131072);

  k_normalize<<<N / 4, 256, 0, stream>>>(x, xq, norms, best);
  k_argmax<<<544, 512, LDS_TOT, stream>>>(xq, best);
  k_dist<<<N / 4, 256, 0, stream>>>(x, norms, best, logd);
  k_final<<<1, 256, 0, stream>>>(logd, out);
}